// Round 19
// baseline (43.314 us; speedup 1.0000x reference)
//
#include <hip/hip_runtime.h>
#include <hip/hip_bf16.h>
#include <stdint.h>

// out[b][co][y][x0] = sum_{ci,ky,kx} x[b][ci][(y+ky-3)%256][(x0+kx-3)%256] * d[b][co][ci][ky][kx]
// Per (b,y-tile) GEMM with ky OUT of K: for each input row i, tmp_o += X[ci16][i][u] * w[ky=i-o]
// K = 16 ci per MFMA (no ky padding). Each A-read fans out to <=4 ky; each B-reg to <=4 rows:
// 17 b128 reads per 28 MFMAs per wave-chunk (vs v9's 20/16) -> attacks the measured LDS floor
// (r10/r16 PMC + cycle audit: LDS b128 service ~40% of chunk time, MfmaUtil 17%).
// epilogue: out[x0] = sum_kx tmp[(x0+kx-3)&255][co*8+kx]  (v9 verified, barrier-first).
// MFMA 32x32x16 bf16; A/B k-slot (s = lh*8+j <-> ci = c*16+s) same verified principle as r3-r6.

constexpr int NB = 8, CIN = 64, HH = 256, WW = 256, CO = 3, KK = 7;
constexpr int R = 8;              // output rows per block
constexpr int XROWS = 14;         // staged input rows y0-3 .. y0+10
constexpr int CIC = 16;           // ci per chunk = MFMA K
constexpr int NCH = CIN / CIC;    // 4
constexpr int XLBYTES = XROWS * 256 * CIC * 2;   // 114688 (single buffer)
constexpr int NBF = KK * NCH;     // 28 B fragments (ky 0..6 x chunk)
constexpr int SMEMSZ = XLBYTES + NBF * 64 * 16;  // 143360; tmp f32[4][256][33]=135168 aliases

typedef short bf16x8 __attribute__((ext_vector_type(8)));
typedef float f32x16 __attribute__((ext_vector_type(16)));

__device__ inline uint16_t f2bf(float f) {
    union { __hip_bfloat16 h; uint16_t u; } cv;
    cv.h = __float2bfloat16(f);          // HW RNE convert
    return cv.u;
}
// involution on 0..255 (32B-unit index): bits[3:0] ^= bits[7:4] (v9-validated family)
__device__ inline int uswz(int u) { return u ^ ((u >> 4) & 15); }

__global__ __launch_bounds__(1024, 4)
void conv_kyfan(const float* __restrict__ x, const float* __restrict__ d,
                float* __restrict__ outp) {
    __shared__ char smem[SMEMSZ];
    uint16_t* Bl  = (uint16_t*)(smem + XLBYTES);
    float*    tmp = (float*)smem;                    // [4][256][33] (epilogue alias)

    const int tid  = threadIdx.x;
    const int lane = tid & 63, wv = tid >> 6;        // 16 waves
    const int m    = wv & 7;                         // m-frag (u block m*32)
    const int rg   = wv >> 3;                        // output-row group (4 rows each)
    const int l31  = lane & 31, lh = lane >> 5;

    // XCD-pinned: image b = blk%8; its 32 blocks cover adjacent y-tiles (halos share L2).
    const int blk = blockIdx.x;
    const int b   = blk & 7;
    const int y0  = (blk >> 3) * R;

    const float* xb = x + (size_t)b * CIN * HH * WW;
    const float* db = d + (size_t)b * CO * CIN * KK * KK;

    f32x16 acc[4];
    #pragma unroll
    for (int o = 0; o < 4; ++o)
        #pragma unroll
        for (int i = 0; i < 16; ++i) acc[o][i] = 0.f;

    // ---- stage chunk c (16 ci) into the single X buffer: [r][uswz(u32)][ci16] 32B units ----
    auto stageX = [&](int c) {
        #pragma unroll
        for (int k = 0; k < 2; ++k) {
            const int it = tid + k * 1024;           // 1792 items = 14 r x 64 q x 2 h
            if (it < XROWS * 128) {
                const int r = it >> 7, rem = it & 127;
                const int q = rem >> 1, h = rem & 1;
                const int row = (y0 + r - 3) & (HH - 1);
                const float* p = xb + ((size_t)(c * CIC + h * 8) * HH + row) * WW + q * 4;
                float4 v[8];
                #pragma unroll
                for (int j = 0; j < 8; ++j)
                    v[j] = *reinterpret_cast<const float4*>(p + (size_t)j * HH * WW);
                #pragma unroll
                for (int t = 0; t < 4; ++t) {
                    uint4 pk;
                    pk.x = (uint32_t)f2bf(((const float*)&v[0])[t]) | ((uint32_t)f2bf(((const float*)&v[1])[t]) << 16);
                    pk.y = (uint32_t)f2bf(((const float*)&v[2])[t]) | ((uint32_t)f2bf(((const float*)&v[3])[t]) << 16);
                    pk.z = (uint32_t)f2bf(((const float*)&v[4])[t]) | ((uint32_t)f2bf(((const float*)&v[5])[t]) << 16);
                    pk.w = (uint32_t)f2bf(((const float*)&v[6])[t]) | ((uint32_t)f2bf(((const float*)&v[7])[t]) << 16);
                    const int us = uswz(q * 4 + t);
                    *reinterpret_cast<uint4*>(smem + ((size_t)r * 256 + us) * 32 + h * 16) = pk;
                }
            }
        }
    };

    // ---- compute chunk c: B hoisted to regs (static idx), A fans out over ky ----
    auto compute = [&](int c) {
        bf16x8 bf[KK];
        #pragma unroll
        for (int ky = 0; ky < KK; ++ky)
            bf[ky] = *reinterpret_cast<const bf16x8*>(&Bl[(size_t)((ky * NCH + c) * 64 + lane) * 8]);
        const int ubase = uswz(m * 32 + l31) * 32 + lh * 16;   // byte offset in row
        #pragma unroll
        for (int r = 0; r < 10; ++r) {               // staged row i = 4*rg + r
            const bf16x8 a = *reinterpret_cast<const bf16x8*>(
                smem + ((size_t)(4 * rg + r) * 256) * 32 + ubase);
            #pragma unroll
            for (int o = 0; o < 4; ++o) {            // ky = r - o, valid 0..6
                const int ky = r - o;
                if (ky < 0 || ky >= KK) continue;
                acc[o] = __builtin_amdgcn_mfma_f32_32x32x16_bf16(a, bf[ky], acc[o], 0, 0, 0);
            }
        }
    };

    // ---- prologue: stage chunk 0 + all 28 B frags (slot s = lh*8+j <-> ci, both sides) ----
    stageX(0);
    #pragma unroll
    for (int k = 0; k < 2; ++k) {
        const int s = tid + k * 1024;                // 1792 slots = 28 frags x 64 lanes
        if (s < NBF * 64) {
            const int fi = s >> 6, ln = s & 63;
            const int ky = fi >> 2, ch = fi & 3;     // fi = ky*4 + ch
            const int n = ln & 31, lh2 = ln >> 5;
            const int co = n >> 3, kx = n & 7;
            uint16_t vals[8];
            #pragma unroll
            for (int j = 0; j < 8; ++j) {
                const int ci = ch * CIC + lh2 * 8 + j;
                float v = 0.f;
                if (co < CO && kx < KK)
                    v = db[((size_t)co * CIN + ci) * (KK * KK) + ky * KK + kx];
                vals[j] = f2bf(v);
            }
            uint4 pk;
            pk.x = (uint32_t)vals[0] | ((uint32_t)vals[1] << 16);
            pk.y = (uint32_t)vals[2] | ((uint32_t)vals[3] << 16);
            pk.z = (uint32_t)vals[4] | ((uint32_t)vals[5] << 16);
            pk.w = (uint32_t)vals[6] | ((uint32_t)vals[7] << 16);
            *reinterpret_cast<uint4*>(&Bl[(size_t)(fi * 64 + ln) * 8]) = pk;
        }
    }

    // ---- main loop: single buffer, 2 barriers/chunk (4 chunks) ----
    for (int c = 0; c < NCH; ++c) {
        __syncthreads();                             // stage(c)+B visible
        compute(c);
        if (c + 1 < NCH) {
            __syncthreads();                         // compute reads done before overwrite
            stageX(c + 1);
        }
    }

    // ---- epilogue (v9 verified, barrier-first): 2 passes x 4 rows ----
    for (int p = 0; p < 2; ++p) {
        __syncthreads();                             // prior compute/reduce reads done
        if (rg == p) {
            #pragma unroll
            for (int o = 0; o < 4; ++o)
                #pragma unroll
                for (int reg = 0; reg < 16; ++reg) {
                    const int rowloc = (reg & 3) + 8 * (reg >> 2) + 4 * lh;
                    const int u = m * 32 + rowloc;
                    tmp[((size_t)o * 256 + u) * 33 + l31] = acc[o][reg];
                }
        }
        __syncthreads();
        #pragma unroll
        for (int it0 = 0; it0 < 3; ++it0) {
            const int it = tid + it0 * 1024;
            if (it < 4 * CO * 256) {                 // 3072 items
                const int rr  = it / (CO * 256);
                const int rem = it - rr * (CO * 256);
                const int co  = rem >> 8, x0 = rem & 255;
                float s = 0.f;
                #pragma unroll
                for (int kx = 0; kx < 7; ++kx)
                    s += tmp[((size_t)rr * 256 + ((x0 + kx - 3) & 255)) * 33 + co * 8 + kx];
                outp[(((size_t)b * CO + co) * HH + (y0 + p * 4 + rr)) * WW + x0] = s;
            }
        }
    }
}

extern "C" void kernel_launch(void* const* d_in, const int* in_sizes, int n_in,
                              void* d_out, int out_size, void* d_ws, size_t ws_size,
                              hipStream_t stream) {
    const float* x = (const float*)d_in[0];
    const float* d = (const float*)d_in[1];
    float* outp = (float*)d_out;
    conv_kyfan<<<dim3(NB * (HH / R)), 1024, 0, stream>>>(x, d, outp);
}

// Round 20
// 39.364 us; speedup vs baseline: 1.1004x; 1.1004x over previous
//
#include <hip/hip_runtime.h>
#include <hip/hip_bf16.h>
#include <stdint.h>

// FINAL (v9, session best: 38.8us r13, 39.1us r18 — reproduced, replay-stable).
// out[b][co][y][x0] = sum_{ci,ky,kx} x[b][ci][(y+ky-3)%256][(x0+kx-3)%256] * d[b][co][ci][ky][kx]
// Per (b,y-tile) GEMM: tmp[u][n=co*8+kx] = sum_{ci,ky} X[ci][(y+ky-3)%256][u] * w[co][ci][ky][kx]
// epilogue: out[x0] = sum_kx tmp[(x0+kx-3)&255][co*8+kx].  MFMA 32x32x16 bf16 (verified r3-r6,r12).
//   1. full 4-bit unit swizzle u^=(u>>4)&15: staging ds_write_b128 covers all 8 bank groups
//      (killed the 2.75M SQ_LDS_BANK_CONFLICT measured in r10); frag reads broadcast-free.
//   2. epilogue 2 passes x 4 rows (tmp[4][256][33] aliases Xl+Bl after last compute).
// Session: 8 structural alternatives (demand reduction x2, register tiling, barrier
// decorrelation, occupancy, producer/consumer, register-held async staging x3, ky-fanout)
// all regressed or spilled. ~39us is this formulation's phase-serialization floor
// (r10/r16 PMC: input L3-resident, no pipe >21%, latency-bound at the barrier drain;
// f32->bf16 convert forces the VGPR round-trip, register budget forbids deeper pipelining).

constexpr int NB = 8, CIN = 64, HH = 256, WW = 256, CO = 3, KK = 7;
constexpr int R = 8;             // output rows per block
constexpr int XROWS = 14;        // staged rows r=0..13 (input y0-3 .. y0+10)
constexpr int CI_CHUNK = 8;
constexpr int NCH = CIN / CI_CHUNK;
constexpr int XBUF = XROWS * 256 * 8;    // u16 elements per X buffer (28672)

typedef short bf16x8 __attribute__((ext_vector_type(8)));
typedef float f32x16 __attribute__((ext_vector_type(16)));

__device__ inline uint16_t f2bf(float f) {
    union { __hip_bfloat16 h; uint16_t u; } cv;
    cv.h = __float2bfloat16(f);          // HW RNE convert
    return cv.u;
}
// involution on 0..255 (16B-unit index): bits[3:0] ^= bits[7:4].
__device__ inline int uswz(int u) { return u ^ ((u >> 4) & 15); }

// LDS: Xl[2][14][256][8] bf16 = 114688 B | Bl[32][64][8] bf16 = 32768 B  (147456 total)
// epilogue tmp f32[4][256][33] = 135168 B aliases Xl+Bl (after last compute).
__global__ __launch_bounds__(1024, 4)
void conv_mfma_v9(const float* __restrict__ x, const float* __restrict__ d,
                  float* __restrict__ outp) {
    __shared__ char smem[2 * XBUF * 2 + 32 * 64 * 8 * 2];
    uint16_t* Xl  = (uint16_t*)smem;
    uint16_t* Bl  = (uint16_t*)(smem + 2 * XBUF * 2);
    float*    tmp = (float*)smem;                      // [4][256][33]

    const int tid  = threadIdx.x;
    const int lane = tid & 63, wv = tid >> 6;          // 16 waves
    const int y_t  = wv >> 1, xh = wv & 1;
    const int l31  = lane & 31, lh = lane >> 5;

    // XCD swizzle: XCD (blk%8) owns image b; its 32 blocks cover adjacent y-tiles.
    const int blk = blockIdx.x;
    const int b   = blk & 7;
    const int y0  = (blk >> 3) * R;

    const float* xb = x + (size_t)b * CIN * HH * WW;
    const float* db = d + (size_t)b * CO * CIN * KK * KK;

    f32x16 acc[4];
    #pragma unroll
    for (int m = 0; m < 4; ++m)
        #pragma unroll
        for (int i = 0; i < 16; ++i) acc[m][i] = 0.f;

    // ---- stage chunk c of X into buffer `buf` (unified r5-proven phase) ----
    auto stageX = [&](int c, int buf) {
        if (tid < XROWS * 64) {                        // 896 active threads
            const int r = tid >> 6, q = tid & 63;
            const int row = (y0 + r - 3) & (HH - 1);
            const float* p = xb + ((size_t)(c * CI_CHUNK) * HH + row) * WW + q * 4;
            float4 v[8];
            #pragma unroll
            for (int j = 0; j < 8; ++j)
                v[j] = *reinterpret_cast<const float4*>(p + (size_t)j * HH * WW);
            uint16_t* dst = Xl + (size_t)buf * XBUF + (size_t)r * 256 * 8;
            #pragma unroll
            for (int t = 0; t < 4; ++t) {
                uint4 pk;
                pk.x = (uint32_t)f2bf(((const float*)&v[0])[t]) | ((uint32_t)f2bf(((const float*)&v[1])[t]) << 16);
                pk.y = (uint32_t)f2bf(((const float*)&v[2])[t]) | ((uint32_t)f2bf(((const float*)&v[3])[t]) << 16);
                pk.z = (uint32_t)f2bf(((const float*)&v[4])[t]) | ((uint32_t)f2bf(((const float*)&v[5])[t]) << 16);
                pk.w = (uint32_t)f2bf(((const float*)&v[6])[t]) | ((uint32_t)f2bf(((const float*)&v[7])[t]) << 16);
                const int us = uswz(q * 4 + t);        // full 8-group spread
                *reinterpret_cast<uint4*>(dst + (size_t)us * 8) = pk;
            }
        }
    };

    // ---- compute chunk c from buffer `buf` ----
    auto compute = [&](int c, int buf) {
        const uint16_t* Xb = Xl + (size_t)buf * XBUF;
        #pragma unroll
        for (int ks = 0; ks < 4; ++ks) {
            const int ky = ks * 2 + lh;
            int r = y_t + ky;                          // <= 14
            if (r >= XROWS) r = 0;                     // only y_t=7,ky=7 (zero weight)
            const int fi = c * 4 + ks;
            const bf16x8 bfrag = *reinterpret_cast<const bf16x8*>(&Bl[(size_t)(fi * 64 + lane) * 8]);
            #pragma unroll
            for (int m = 0; m < 4; ++m) {
                const int us = uswz(xh * 128 + m * 32 + l31);
                const bf16x8 afrag = *reinterpret_cast<const bf16x8*>(&Xb[((size_t)r * 256 + us) * 8]);
                acc[m] = __builtin_amdgcn_mfma_f32_32x32x16_bf16(afrag, bfrag, acc[m], 0, 0, 0);
            }
        }
    };

    // ---- prologue: X chunk 0 + ALL of B (32 frags, fragment order) ----
    stageX(0, 0);
    #pragma unroll
    for (int q2 = 0; q2 < 2; ++q2) {
        const int s = tid + q2 * 1024;                 // 2048 slots
        const int fi = s >> 6, ln = s & 63;
        const int cc8 = fi >> 2, ks = fi & 3;
        const int h = ln >> 5, n = ln & 31;
        const int ky = ks * 2 + h, co = n >> 3, kx = n & 7;
        uint16_t vals[8];
        #pragma unroll
        for (int j = 0; j < 8; ++j) {
            float v = 0.f;
            if (co < CO && kx < KK && ky < KK)
                v = db[((size_t)co * CIN + cc8 * 8 + j) * (KK * KK) + ky * KK + kx];
            vals[j] = f2bf(v);
        }
        uint4 pk;
        pk.x = (uint32_t)vals[0] | ((uint32_t)vals[1] << 16);
        pk.y = (uint32_t)vals[2] | ((uint32_t)vals[3] << 16);
        pk.z = (uint32_t)vals[4] | ((uint32_t)vals[5] << 16);
        pk.w = (uint32_t)vals[6] | ((uint32_t)vals[7] << 16);
        *reinterpret_cast<uint4*>(&Bl[(size_t)(fi * 64 + ln) * 8]) = pk;
    }

    // ---- main loop (r5-proven): barrier ; stage(c+1) ; compute(c) ----
    for (int c = 0; c < NCH; ++c) {
        __syncthreads();                               // buf[c&1] writes visible
        if (c + 1 < NCH) stageX(c + 1, (c + 1) & 1);   // writes opposite buffer
        compute(c, c & 1);
    }

    // ---- epilogue: 2 passes x 4 rows; tmp[4][256][33] aliases Xl+Bl ----
    for (int p = 0; p < 2; ++p) {
        __syncthreads();                               // prior compute/reduce reads done
        if ((y_t >> 2) == p) {
            const int rr = y_t & 3;
            #pragma unroll
            for (int m = 0; m < 4; ++m)
                #pragma unroll
                for (int reg = 0; reg < 16; ++reg) {
                    const int rowloc = (reg & 3) + 8 * (reg >> 2) + 4 * lh;
                    const int u = xh * 128 + m * 32 + rowloc;
                    tmp[((size_t)rr * 256 + u) * 33 + l31] = acc[m][reg];
                }
        }
        __syncthreads();
        #pragma unroll
        for (int it0 = 0; it0 < 3; ++it0) {
            const int it = tid + it0 * 1024;
            if (it < 4 * CO * 256) {                   // 3072 items
                const int rr  = it / (CO * 256);
                const int rem = it - rr * (CO * 256);
                const int co  = rem >> 8, x0 = rem & 255;
                float s = 0.f;
                #pragma unroll
                for (int kx = 0; kx < 7; ++kx)
                    s += tmp[((size_t)rr * 256 + ((x0 + kx - 3) & 255)) * 33 + co * 8 + kx];
                outp[(((size_t)b * CO + co) * HH + (y0 + p * 4 + rr)) * WW + x0] = s;
            }
        }
    }
}

extern "C" void kernel_launch(void* const* d_in, const int* in_sizes, int n_in,
                              void* d_out, int out_size, void* d_ws, size_t ws_size,
                              hipStream_t stream) {
    const float* x = (const float*)d_in[0];
    const float* d = (const float*)d_in[1];
    float* outp = (float*)d_out;
    conv_mfma_v9<<<dim3(NB * (HH / R)), 1024, 0, stream>>>(x, d, outp);
}